// Round 1
// baseline (1889.348 us; speedup 1.0000x reference)
//
#include <hip/hip_runtime.h>
#include <hip/hip_bf16.h>

#define N_NODES 50000
#define N_EDGES 1600000
#define HEADS 8
#define DH 16
#define DIM 128            // in-dim and out-dim of both layers (HEADS*DH)
#define NEG_SLOPE 0.01f

// ---------------------------------------------------------------------------
// proj: z[n,h,k] = sum_d x[n,d] * W[h,d,k];  s_src[n,h] = sum_k z*a_src[h,k];
// s_dst likewise. W staged in LDS (h-stride padded +8 floats -> 2-way bank
// alias on the per-d read, which is free). x staged 16 nodes at a time; the
// per-d x read is a wave-broadcast (same address across lanes).
// ---------------------------------------------------------------------------
__global__ __launch_bounds__(256, 2) void proj_kernel(
    const float* __restrict__ x,      // [N,128]
    const float* __restrict__ W,      // [8][128][16]
    const float* __restrict__ a_src,  // [8][16] flat
    const float* __restrict__ a_dst,  // [8][16] flat
    float* __restrict__ z,            // [N,128]
    float* __restrict__ s_src,        // [N,8]
    float* __restrict__ s_dst)        // [N,8]
{
    __shared__ float Wl[8 * 2056];    // h stride 2056 (=2048+8 pad)
    __shared__ float xl[16 * 128];
    __shared__ float asl[128], adl[128];

    const int t = threadIdx.x;
    for (int i = t; i < 8 * 128 * 16; i += 256) {
        int h = i >> 11;
        int r = i & 2047;
        Wl[h * 2056 + r] = W[i];
    }
    if (t < 128) { asl[t] = a_src[t]; adl[t] = a_dst[t]; }
    __syncthreads();

    const int c  = t & 127;           // output channel
    const int ng = t >> 7;            // node sub-group (0/1)
    const int h  = c >> 4;
    const int k  = c & 15;
    const float as = asl[c];
    const float ad = adl[c];
    const float* wp = &Wl[h * 2056 + k];

    for (int n0 = blockIdx.x * 16; n0 < N_NODES; n0 += gridDim.x * 16) {
        __syncthreads();              // protect xl reuse across tiles
        const int nrem = min(16, N_NODES - n0);
        for (int i = t; i < nrem * 128; i += 256) xl[i] = x[n0 * 128 + i];
        __syncthreads();

        float acc[8];
#pragma unroll
        for (int j = 0; j < 8; j++) acc[j] = 0.f;

        for (int d = 0; d < 128; d++) {
            const float wv = wp[d * 16];
            const float* xr = &xl[(ng * 8) * 128 + d];
#pragma unroll
            for (int j = 0; j < 8; j++)
                acc[j] = fmaf(wv, xr[j * 128], acc[j]);
        }

#pragma unroll
        for (int j = 0; j < 8; j++) {
            const int n = n0 + ng * 8 + j;
            const bool valid = (n < N_NODES);
            if (valid) z[n * 128 + c] = acc[j];
            float ss = acc[j] * as;
            float sd = acc[j] * ad;
#pragma unroll
            for (int m = 1; m < 16; m <<= 1) {
                ss += __shfl_xor(ss, m);
                sd += __shfl_xor(sd, m);
            }
            if (k == 0 && valid) {
                s_src[n * 8 + h] = ss;
                s_dst[n * 8 + h] = sd;
            }
        }
    }
}

// ---------------------------------------------------------------------------
// edge: for each (edge e, channel c): w = exp(leaky_relu(s_src[src]+s_dst[dst]))
// (softmax is shift-invariant -> no segment_max pass needed; scores are O(10)).
// Scatter: num[dst,c] += w * z[src,c]; denom[dst,h] += w (one lane per head).
// Wave = 64 consecutive channels of one edge -> broadcast index/score loads,
// contiguous 256B z gather, coalesced atomic addresses.
// ---------------------------------------------------------------------------
__global__ __launch_bounds__(256, 8) void edge_kernel(
    const int* __restrict__ src, const int* __restrict__ dst,
    const float* __restrict__ z,
    const float* __restrict__ s_src, const float* __restrict__ s_dst,
    float* __restrict__ num,          // [N,128]
    float* __restrict__ denom)        // [N,8]
{
    const int total = N_EDGES * 128;  // 204.8M < 2^31
    for (int idx = blockIdx.x * 256 + threadIdx.x; idx < total;
         idx += gridDim.x * 256) {
        const int e = idx >> 7;
        const int c = idx & 127;
        const int h = c >> 4;
        const int se = src[e];
        const int de = dst[e];
        float s = s_src[se * 8 + h] + s_dst[de * 8 + h];
        s = s > 0.f ? s : NEG_SLOPE * s;
        const float w = __expf(s);
        if ((c & 15) == 0) atomicAdd(&denom[de * 8 + h], w);
        const float zv = z[se * 128 + c];
        atomicAdd(&num[de * 128 + c], w * zv);
    }
}

// ---------------------------------------------------------------------------
// finalize: out = num/denom (0 for empty segments, matching reference), with
// optional ELU (layer 1 only).
// ---------------------------------------------------------------------------
__global__ __launch_bounds__(256, 8) void finalize_kernel(
    const float* __restrict__ num, const float* __restrict__ denom,
    float* __restrict__ out, const int apply_elu)
{
    for (int idx = blockIdx.x * 256 + threadIdx.x; idx < N_NODES * 128;
         idx += gridDim.x * 256) {
        const int n = idx >> 7;
        const int h = (idx & 127) >> 4;
        const float d = denom[n * 8 + h];
        const float v = num[idx];
        float o = (d == 0.f) ? 0.f : v / d;
        if (apply_elu) o = o > 0.f ? o : expm1f(o);
        out[idx] = o;
    }
}

extern "C" void kernel_launch(void* const* d_in, const int* in_sizes, int n_in,
                              void* d_out, int out_size, void* d_ws, size_t ws_size,
                              hipStream_t stream) {
    const float* x    = (const float*)d_in[0];
    const int*   src  = (const int*)d_in[1];
    const int*   dst  = (const int*)d_in[2];
    const float* W1   = (const float*)d_in[3];
    const float* a1s  = (const float*)d_in[4];
    const float* a1d  = (const float*)d_in[5];
    const float* W2   = (const float*)d_in[6];
    const float* a2s  = (const float*)d_in[7];
    const float* a2d  = (const float*)d_in[8];
    float* out = (float*)d_out;

    // workspace layout (floats)
    float* z    = (float*)d_ws;             // N*128
    float* num  = z    + N_NODES * 128;     // N*128
    float* ssrc = num  + N_NODES * 128;     // N*8
    float* sdst = ssrc + N_NODES * 8;       // N*8
    float* den  = sdst + N_NODES * 8;       // N*8

    const int PROJ_GRID = 1024;
    const int EDGE_GRID = 8192;
    const int FIN_GRID  = 4096;

    // ---- layer 1 ----
    proj_kernel<<<PROJ_GRID, 256, 0, stream>>>(x, W1, a1s, a1d, z, ssrc, sdst);
    hipMemsetAsync(num, 0, (size_t)N_NODES * 128 * 4, stream);
    hipMemsetAsync(den, 0, (size_t)N_NODES * 8 * 4, stream);
    edge_kernel<<<EDGE_GRID, 256, 0, stream>>>(src, dst, z, ssrc, sdst, num, den);
    finalize_kernel<<<FIN_GRID, 256, 0, stream>>>(num, den, out, 1);  // out = h1 (ELU)

    // ---- layer 2 (reads h1 from d_out, overwrites d_out at the end) ----
    proj_kernel<<<PROJ_GRID, 256, 0, stream>>>(out, W2, a2s, a2d, z, ssrc, sdst);
    hipMemsetAsync(num, 0, (size_t)N_NODES * 128 * 4, stream);
    hipMemsetAsync(den, 0, (size_t)N_NODES * 8 * 4, stream);
    edge_kernel<<<EDGE_GRID, 256, 0, stream>>>(src, dst, z, ssrc, sdst, num, den);
    finalize_kernel<<<FIN_GRID, 256, 0, stream>>>(num, den, out, 0);
}

// Round 2
// 817.280 us; speedup vs baseline: 2.3118x; 2.3118x over previous
//
#include <hip/hip_runtime.h>
#include <hip/hip_bf16.h>

#define N_NODES 50000
#define N_EDGES 1600000
#define HEADS 8
#define DH 16
#define DIM 128
#define NEG_SLOPE 0.01f

// ---------------------------------------------------------------------------
// proj: z[n,h,k] = sum_d x[n,d] * W[h,d,k];  s_src[n,h], s_dst[n,h] fused.
// (unchanged from R1 — was not a bottleneck)
// ---------------------------------------------------------------------------
__global__ __launch_bounds__(256, 2) void proj_kernel(
    const float* __restrict__ x,
    const float* __restrict__ W,
    const float* __restrict__ a_src,
    const float* __restrict__ a_dst,
    float* __restrict__ z,
    float* __restrict__ s_src,
    float* __restrict__ s_dst)
{
    __shared__ float Wl[8 * 2056];
    __shared__ float xl[16 * 128];
    __shared__ float asl[128], adl[128];

    const int t = threadIdx.x;
    for (int i = t; i < 8 * 128 * 16; i += 256) {
        int h = i >> 11;
        int r = i & 2047;
        Wl[h * 2056 + r] = W[i];
    }
    if (t < 128) { asl[t] = a_src[t]; adl[t] = a_dst[t]; }
    __syncthreads();

    const int c  = t & 127;
    const int ng = t >> 7;
    const int h  = c >> 4;
    const int k  = c & 15;
    const float as = asl[c];
    const float ad = adl[c];
    const float* wp = &Wl[h * 2056 + k];

    for (int n0 = blockIdx.x * 16; n0 < N_NODES; n0 += gridDim.x * 16) {
        __syncthreads();
        const int nrem = min(16, N_NODES - n0);
        for (int i = t; i < nrem * 128; i += 256) xl[i] = x[n0 * 128 + i];
        __syncthreads();

        float acc[8];
#pragma unroll
        for (int j = 0; j < 8; j++) acc[j] = 0.f;

        for (int d = 0; d < 128; d++) {
            const float wv = wp[d * 16];
            const float* xr = &xl[(ng * 8) * 128 + d];
#pragma unroll
            for (int j = 0; j < 8; j++)
                acc[j] = fmaf(wv, xr[j * 128], acc[j]);
        }

#pragma unroll
        for (int j = 0; j < 8; j++) {
            const int n = n0 + ng * 8 + j;
            const bool valid = (n < N_NODES);
            if (valid) z[n * 128 + c] = acc[j];
            float ss = acc[j] * as;
            float sd = acc[j] * ad;
#pragma unroll
            for (int m = 1; m < 16; m <<= 1) {
                ss += __shfl_xor(ss, m);
                sd += __shfl_xor(sd, m);
            }
            if (k == 0 && valid) {
                s_src[n * 8 + h] = ss;
                s_dst[n * 8 + h] = sd;
            }
        }
    }
}

// ---------------------------------------------------------------------------
// CSR build (once, reused by both layers): histogram -> scan -> scatter.
// perm stores the SRC node id of each edge, grouped by dst.
// ---------------------------------------------------------------------------
__global__ __launch_bounds__(256, 8) void hist_kernel(
    const int* __restrict__ dst, int* __restrict__ count)
{
    for (int e = blockIdx.x * 256 + threadIdx.x; e < N_EDGES;
         e += gridDim.x * 256)
        atomicAdd(&count[dst[e]], 1);
}

#define SCAN_T 1024
#define SCAN_CHUNK 49   // 1024*49 = 50176 >= 50000
__global__ __launch_bounds__(SCAN_T, 1) void scan_kernel(
    const int* __restrict__ count,
    int* __restrict__ row_ptr,   // [N+1]
    int* __restrict__ cursor)    // [N]
{
    __shared__ int part[SCAN_T];
    const int t = threadIdx.x;
    const int lo = t * SCAN_CHUNK;
    const int hi = min(lo + SCAN_CHUNK, N_NODES);

    int s = 0;
    for (int i = lo; i < hi; i++) s += count[i];
    part[t] = s;
    __syncthreads();

    // inclusive Hillis-Steele scan over 1024 partials
    int v = s;
    for (int off = 1; off < SCAN_T; off <<= 1) {
        int add = (t >= off) ? part[t - off] : 0;
        __syncthreads();
        v += add;
        part[t] = v;
        __syncthreads();
    }
    int run = v - s;  // exclusive offset for this thread's chunk
    for (int i = lo; i < hi; i++) {
        row_ptr[i] = run;
        cursor[i]  = run;
        run += count[i];
    }
    if (t == SCAN_T - 1) row_ptr[N_NODES] = run;
}

__global__ __launch_bounds__(256, 8) void scatter_kernel(
    const int* __restrict__ src, const int* __restrict__ dst,
    int* __restrict__ cursor, int* __restrict__ perm)
{
    for (int e = blockIdx.x * 256 + threadIdx.x; e < N_EDGES;
         e += gridDim.x * 256) {
        const int d = dst[e];
        const int p = atomicAdd(&cursor[d], 1);
        perm[p] = src[e];
    }
}

// ---------------------------------------------------------------------------
// gather: one block (128 threads) per dst node; thread = one channel.
// acc += w * z[src,c] over incoming edges, w = exp(leaky_relu(s_src+s_dst))
// (softmax shift-invariance -> no max pass). Fuses normalize + ELU; writes
// final output directly. Zero atomics.
// ---------------------------------------------------------------------------
__global__ __launch_bounds__(128, 8) void gather_kernel(
    const int* __restrict__ row_ptr, const int* __restrict__ perm,
    const float* __restrict__ z,
    const float* __restrict__ s_src, const float* __restrict__ s_dst,
    float* __restrict__ out, const int apply_elu)
{
    const int n = blockIdx.x;
    const int c = threadIdx.x;
    const int h = c >> 4;
    const int start = row_ptr[n];
    const int end   = row_ptr[n + 1];
    const float sd = s_dst[n * 8 + h];

    float acc = 0.f, wsum = 0.f;
    int se_next = (start < end) ? perm[start] : 0;
    for (int j = start; j < end; j++) {
        const int se = se_next;
        se_next = (j + 1 < end) ? perm[j + 1] : 0;
        float s = s_src[se * 8 + h] + sd;
        s = s > 0.f ? s : NEG_SLOPE * s;
        const float w = __expf(s);
        wsum += w;
        acc = fmaf(w, z[se * 128 + c], acc);
    }

    float o = (end > start) ? acc / wsum : 0.f;
    if (apply_elu) o = o > 0.f ? o : expm1f(o);
    out[n * 128 + c] = o;
}

extern "C" void kernel_launch(void* const* d_in, const int* in_sizes, int n_in,
                              void* d_out, int out_size, void* d_ws, size_t ws_size,
                              hipStream_t stream) {
    const float* x    = (const float*)d_in[0];
    const int*   src  = (const int*)d_in[1];
    const int*   dst  = (const int*)d_in[2];
    const float* W1   = (const float*)d_in[3];
    const float* a1s  = (const float*)d_in[4];
    const float* a1d  = (const float*)d_in[5];
    const float* W2   = (const float*)d_in[6];
    const float* a2s  = (const float*)d_in[7];
    const float* a2d  = (const float*)d_in[8];
    float* out = (float*)d_out;

    // workspace layout
    float* z     = (float*)d_ws;                 // N*128 floats
    float* ssrc  = z    + N_NODES * 128;         // N*8
    float* sdst  = ssrc + N_NODES * 8;           // N*8
    int*   count = (int*)(sdst + N_NODES * 8);   // N
    int*   rowp  = count + N_NODES;              // N+1
    int*   curs  = rowp + N_NODES + 1;           // N
    int*   perm  = curs + N_NODES;               // E

    const int PROJ_GRID = 1024;
    const int EB_GRID   = 4096;

    // ---- CSR build (shared by both layers) ----
    hipMemsetAsync(count, 0, (size_t)N_NODES * 4, stream);
    hist_kernel<<<EB_GRID, 256, 0, stream>>>(dst, count);
    scan_kernel<<<1, SCAN_T, 0, stream>>>(count, rowp, curs);
    scatter_kernel<<<EB_GRID, 256, 0, stream>>>(src, dst, curs, perm);

    // ---- layer 1 ----
    proj_kernel<<<PROJ_GRID, 256, 0, stream>>>(x, W1, a1s, a1d, z, ssrc, sdst);
    gather_kernel<<<N_NODES, 128, 0, stream>>>(rowp, perm, z, ssrc, sdst, out, 1);

    // ---- layer 2 ----
    proj_kernel<<<PROJ_GRID, 256, 0, stream>>>(out, W2, a2s, a2d, z, ssrc, sdst);
    gather_kernel<<<N_NODES, 128, 0, stream>>>(rowp, perm, z, ssrc, sdst, out, 0);
}

// Round 3
// 509.887 us; speedup vs baseline: 3.7054x; 1.6029x over previous
//
#include <hip/hip_runtime.h>
#include <hip/hip_bf16.h>

#define N_NODES 50000
#define N_EDGES 1600000
#define NEG_SLOPE 0.01f
#define WPAD 136   // k-stride (fp16 elems) for LDS-staged W: 272B row = 17*16B (aligned, ~2-way banks)

typedef _Float16 v8h __attribute__((ext_vector_type(8)));
typedef float v4f __attribute__((ext_vector_type(4)));

// ---------------------------------------------------------------------------
// proj: z[n, h*16+col] = sum_d x[n,d] * W[h,d,col], via fp16 MFMA 16x16x32.
// Wave = one 16-node tile x all 128 output channels (8 head-tiles x 4 k-blocks
// = 32 MFMA). A-frag: lane holds x[n0 + (l&15)][kb*32 + (l>>4)*8 + j] (direct
// global load + cvt). B-frag from LDS W_t[ch][k] fp16. D: col=lane&15,
// row=(lane>>4)*4+reg (m89-verified). z written as fp16.
// ---------------------------------------------------------------------------
__global__ __launch_bounds__(256) void proj_mfma_kernel(
    const float* __restrict__ x,      // [N,128] fp32
    const float* __restrict__ W,      // [8][128][16] fp32
    _Float16* __restrict__ z)         // [N,128] fp16
{
    __shared__ _Float16 Wl[128 * WPAD];   // [ch=h*16+col][k]

    const int t = threadIdx.x;
    // stage W transposed: flat i = h*2048 + k*16 + col
    for (int i = t; i < 16384; i += 256) {
        const int h = i >> 11, k = (i >> 4) & 127, col = i & 15;
        Wl[(h * 16 + col) * WPAD + k] = (_Float16)W[i];
    }
    __syncthreads();

    const int wid = t >> 6;
    const int l   = t & 63;
    const int lc  = l & 15;       // A-row / B-col / D-col
    const int kg  = l >> 4;       // k-group 0..3

    const int nwaves = gridDim.x * 4;
    for (int tile = blockIdx.x * 4 + wid; tile < N_NODES / 16; tile += nwaves) {
        const int n0 = tile * 16;
        v4f acc[8];
#pragma unroll
        for (int ht = 0; ht < 8; ht++) acc[ht] = (v4f)0.f;

#pragma unroll
        for (int kb = 0; kb < 4; kb++) {
            const float* xp = &x[(n0 + lc) * 128 + kb * 32 + kg * 8];
            v8h a;
#pragma unroll
            for (int j = 0; j < 8; j++) a[j] = (_Float16)xp[j];
#pragma unroll
            for (int ht = 0; ht < 8; ht++) {
                const v8h b = *(const v8h*)&Wl[(ht * 16 + lc) * WPAD + kb * 32 + kg * 8];
                acc[ht] = __builtin_amdgcn_mfma_f32_16x16x32_f16(a, b, acc[ht], 0, 0, 0);
            }
        }

        // D element (row = 4*kg + i, col = ht*16 + lc)
        _Float16* zp = &z[(n0 + 4 * kg) * 128 + lc];
#pragma unroll
        for (int ht = 0; ht < 8; ht++)
#pragma unroll
            for (int i = 0; i < 4; i++)
                zp[i * 128 + ht * 16] = (_Float16)acc[ht][i];
    }
}

// ---------------------------------------------------------------------------
// score: s_src[n,h] = sum_k z[n,h,k]*a_src[h,k]; s_dst likewise. Vectorized
// 32B z reads, coalesced (h fast-varying across lanes).
// ---------------------------------------------------------------------------
__global__ __launch_bounds__(256) void score_kernel(
    const _Float16* __restrict__ z,
    const float* __restrict__ a_src, const float* __restrict__ a_dst,
    float* __restrict__ s_src, float* __restrict__ s_dst)
{
    __shared__ float asl[128], adl[128];
    const int t = threadIdx.x;
    if (t < 128) { asl[t] = a_src[t]; adl[t] = a_dst[t]; }
    __syncthreads();

    const int idx = blockIdx.x * 256 + t;       // (n,h)
    if (idx >= N_NODES * 8) return;
    const int n = idx >> 3, h = idx & 7;

    const v8h z0 = *(const v8h*)&z[n * 128 + h * 16];
    const v8h z1 = *(const v8h*)&z[n * 128 + h * 16 + 8];
    float ss = 0.f, sd = 0.f;
#pragma unroll
    for (int j = 0; j < 8; j++) {
        ss = fmaf((float)z0[j], asl[h * 16 + j], ss);
        sd = fmaf((float)z0[j], adl[h * 16 + j], sd);
    }
#pragma unroll
    for (int j = 0; j < 8; j++) {
        ss = fmaf((float)z1[j], asl[h * 16 + 8 + j], ss);
        sd = fmaf((float)z1[j], adl[h * 16 + 8 + j], sd);
    }
    s_src[idx] = ss;
    s_dst[idx] = sd;
}

// ---------------------------------------------------------------------------
// CSR build (once): histogram -> scan -> scatter. perm[p] = src node of slot p.
// ---------------------------------------------------------------------------
__global__ __launch_bounds__(256) void hist_kernel(
    const int* __restrict__ dst, int* __restrict__ count)
{
    for (int e = blockIdx.x * 256 + threadIdx.x; e < N_EDGES;
         e += gridDim.x * 256)
        atomicAdd(&count[dst[e]], 1);
}

#define SCAN_T 1024
#define SCAN_CHUNK 49
__global__ __launch_bounds__(SCAN_T, 1) void scan_kernel(
    const int* __restrict__ count, int* __restrict__ row_ptr,
    int* __restrict__ cursor)
{
    __shared__ int part[SCAN_T];
    const int t = threadIdx.x;
    const int lo = t * SCAN_CHUNK;
    const int hi = min(lo + SCAN_CHUNK, N_NODES);

    int s = 0;
    for (int i = lo; i < hi; i++) s += count[i];
    part[t] = s;
    __syncthreads();

    int v = s;
    for (int off = 1; off < SCAN_T; off <<= 1) {
        int add = (t >= off) ? part[t - off] : 0;
        __syncthreads();
        v += add;
        part[t] = v;
        __syncthreads();
    }
    int run = v - s;
    for (int i = lo; i < hi; i++) {
        row_ptr[i] = run;
        cursor[i]  = run;
        run += count[i];
    }
    if (t == SCAN_T - 1) row_ptr[N_NODES] = run;
}

__global__ __launch_bounds__(256) void scatter_kernel(
    const int* __restrict__ src, const int* __restrict__ dst,
    int* __restrict__ cursor, int* __restrict__ perm)
{
    for (int e = blockIdx.x * 256 + threadIdx.x; e < N_EDGES;
         e += gridDim.x * 256) {
        const int d = dst[e];
        const int p = atomicAdd(&cursor[d], 1);
        perm[p] = src[e];
    }
}

// ---------------------------------------------------------------------------
// gather: block (128 thr) per dst node. Per 32-edge chunk: phase 1 computes
// w[e][h] ONCE per (edge,head) into LDS (kills the 16x redundant exp);
// phase 2: lean fp16-z accumulate. Fuses normalize + ELU. Zero atomics.
// ---------------------------------------------------------------------------
__global__ __launch_bounds__(128) void gather_kernel(
    const int* __restrict__ row_ptr, const int* __restrict__ perm,
    const _Float16* __restrict__ z,
    const float* __restrict__ s_src, const float* __restrict__ s_dst,
    float* __restrict__ out, const int apply_elu)
{
    __shared__ int   se_l[32];
    __shared__ float w_l[32][8];

    const int n = blockIdx.x;
    const int t = threadIdx.x;
    const int c = t;
    const int h = t >> 4;
    const int start = row_ptr[n];
    const int end   = row_ptr[n + 1];

    float acc = 0.f, wsum = 0.f;

    for (int j0 = start; j0 < end; j0 += 32) {
        const int cnt = min(32, end - j0);
        __syncthreads();                     // protect LDS reuse across chunks
#pragma unroll
        for (int u = 0; u < 2; u++) {
            const int idx = t + u * 128;
            const int j = idx & 31, hh = idx >> 5;
            if (j < cnt) {
                const int se = perm[j0 + j];
                if (hh == 0) se_l[j] = se;
                float s = s_src[se * 8 + hh] + s_dst[n * 8 + hh];
                s = s > 0.f ? s : NEG_SLOPE * s;
                w_l[j][hh] = __expf(s);
            }
        }
        __syncthreads();
#pragma unroll 4
        for (int j = 0; j < cnt; j++) {
            const float w = w_l[j][h];
            wsum += w;
            acc = fmaf(w, (float)z[se_l[j] * 128 + c], acc);
        }
    }

    float o = (end > start) ? acc / wsum : 0.f;
    if (apply_elu) o = o > 0.f ? o : expm1f(o);
    out[n * 128 + c] = o;
}

extern "C" void kernel_launch(void* const* d_in, const int* in_sizes, int n_in,
                              void* d_out, int out_size, void* d_ws, size_t ws_size,
                              hipStream_t stream) {
    const float* x    = (const float*)d_in[0];
    const int*   src  = (const int*)d_in[1];
    const int*   dst  = (const int*)d_in[2];
    const float* W1   = (const float*)d_in[3];
    const float* a1s  = (const float*)d_in[4];
    const float* a1d  = (const float*)d_in[5];
    const float* W2   = (const float*)d_in[6];
    const float* a2s  = (const float*)d_in[7];
    const float* a2d  = (const float*)d_in[8];
    float* out = (float*)d_out;

    // workspace layout
    _Float16* z  = (_Float16*)d_ws;                       // N*128 fp16
    float* ssrc  = (float*)(z + (size_t)N_NODES * 128);   // N*8 f32
    float* sdst  = ssrc + N_NODES * 8;                    // N*8
    int*   count = (int*)(sdst + N_NODES * 8);            // N
    int*   rowp  = count + N_NODES;                       // N+1
    int*   curs  = rowp + N_NODES + 1;                    // N
    int*   perm  = curs + N_NODES;                        // E

    const int PROJ_GRID  = 391;    // x4 waves, grid-stride over 3125 tiles
    const int SCORE_GRID = (N_NODES * 8 + 255) / 256;
    const int EB_GRID    = 2048;

    // ---- CSR build (shared by both layers) ----
    hipMemsetAsync(count, 0, (size_t)N_NODES * 4, stream);
    hist_kernel<<<EB_GRID, 256, 0, stream>>>(dst, count);
    scan_kernel<<<1, SCAN_T, 0, stream>>>(count, rowp, curs);
    scatter_kernel<<<EB_GRID, 256, 0, stream>>>(src, dst, curs, perm);

    // ---- layer 1 ----
    proj_mfma_kernel<<<PROJ_GRID, 256, 0, stream>>>(x, W1, z);
    score_kernel<<<SCORE_GRID, 256, 0, stream>>>(z, a1s, a1d, ssrc, sdst);
    gather_kernel<<<N_NODES, 128, 0, stream>>>(rowp, perm, z, ssrc, sdst, out, 1);

    // ---- layer 2 ----
    proj_mfma_kernel<<<PROJ_GRID, 256, 0, stream>>>(out, W2, z);
    score_kernel<<<SCORE_GRID, 256, 0, stream>>>(z, a2s, a2d, ssrc, sdst);
    gather_kernel<<<N_NODES, 128, 0, stream>>>(rowp, perm, z, ssrc, sdst, out, 0);
}

// Round 5
// 251.901 us; speedup vs baseline: 7.5004x; 2.0242x over previous
//
#include <hip/hip_runtime.h>
#include <hip/hip_bf16.h>

#define N_NODES 50000
#define N_EDGES 1600000
#define NEG_SLOPE 0.01f
#define WPAD 136   // k-stride (fp16) for LDS-staged W

#define NBKT 256   // dst buckets
#define BKTW 196   // bucket width: 196*256 = 50176 >= 50000
#define NBLK1 200  // pass-1 blocks
#define CHUNK1 8000 // 200*8000 = 1.6M edges exactly

typedef _Float16 v8h __attribute__((ext_vector_type(8)));
typedef float v4f __attribute__((ext_vector_type(4)));

// ---------------------------------------------------------------------------
// proj: z[n, h*16+col] = sum_d x[n,d] * W[h,d,col], fp16 MFMA 16x16x32.
// ---------------------------------------------------------------------------
__global__ __launch_bounds__(256) void proj_mfma_kernel(
    const float* __restrict__ x,
    const float* __restrict__ W,
    _Float16* __restrict__ z)
{
    __shared__ _Float16 Wl[128 * WPAD];

    const int t = threadIdx.x;
    for (int i = t; i < 16384; i += 256) {
        const int h = i >> 11, k = (i >> 4) & 127, col = i & 15;
        Wl[(h * 16 + col) * WPAD + k] = (_Float16)W[i];
    }
    __syncthreads();

    const int wid = t >> 6;
    const int l   = t & 63;
    const int lc  = l & 15;
    const int kg  = l >> 4;

    const int nwaves = gridDim.x * 4;
    for (int tile = blockIdx.x * 4 + wid; tile < N_NODES / 16; tile += nwaves) {
        const int n0 = tile * 16;
        v4f acc[8];
#pragma unroll
        for (int ht = 0; ht < 8; ht++) acc[ht] = (v4f)0.f;

#pragma unroll
        for (int kb = 0; kb < 4; kb++) {
            const float* xp = &x[(n0 + lc) * 128 + kb * 32 + kg * 8];
            v8h a;
#pragma unroll
            for (int j = 0; j < 8; j++) a[j] = (_Float16)xp[j];
#pragma unroll
            for (int ht = 0; ht < 8; ht++) {
                const v8h b = *(const v8h*)&Wl[(ht * 16 + lc) * WPAD + kb * 32 + kg * 8];
                acc[ht] = __builtin_amdgcn_mfma_f32_16x16x32_f16(a, b, acc[ht], 0, 0, 0);
            }
        }

        _Float16* zp = &z[(n0 + 4 * kg) * 128 + lc];
#pragma unroll
        for (int ht = 0; ht < 8; ht++)
#pragma unroll
            for (int i = 0; i < 4; i++)
                zp[i * 128 + ht * 16] = (_Float16)acc[ht][i];
    }
}

// ---------------------------------------------------------------------------
// score: s_src[n,h], s_dst[n,h] from fp16 z.
// ---------------------------------------------------------------------------
__global__ __launch_bounds__(256) void score_kernel(
    const _Float16* __restrict__ z,
    const float* __restrict__ a_src, const float* __restrict__ a_dst,
    float* __restrict__ s_src, float* __restrict__ s_dst)
{
    __shared__ float asl[128], adl[128];
    const int t = threadIdx.x;
    if (t < 128) { asl[t] = a_src[t]; adl[t] = a_dst[t]; }
    __syncthreads();

    const int idx = blockIdx.x * 256 + t;
    if (idx >= N_NODES * 8) return;
    const int n = idx >> 3, h = idx & 7;

    const v8h z0 = *(const v8h*)&z[n * 128 + h * 16];
    const v8h z1 = *(const v8h*)&z[n * 128 + h * 16 + 8];
    float ss = 0.f, sd = 0.f;
#pragma unroll
    for (int j = 0; j < 8; j++) {
        ss = fmaf((float)z0[j], asl[h * 16 + j], ss);
        sd = fmaf((float)z0[j], adl[h * 16 + j], sd);
    }
#pragma unroll
    for (int j = 0; j < 8; j++) {
        ss = fmaf((float)z1[j], asl[h * 16 + 8 + j], ss);
        sd = fmaf((float)z1[j], adl[h * 16 + 8 + j], sd);
    }
    s_src[idx] = ss;
    s_dst[idx] = sd;
}

// ---------------------------------------------------------------------------
// CSR build v2: two-level bucket sort; all scatter writes block-local.
// k1: per-block LDS histogram over 256 dst-buckets -> bh[bucket][blk]
// ---------------------------------------------------------------------------
__global__ __launch_bounds__(256) void hist_bucket_kernel(
    const int* __restrict__ dst, int* __restrict__ bh)
{
    __shared__ int lhist[NBKT];
    const int t = threadIdx.x, blk = blockIdx.x;
    lhist[t] = 0;
    __syncthreads();
    const int e0 = blk * CHUNK1, e1 = e0 + CHUNK1;
    for (int e = e0 + t; e < e1; e += 256)
        atomicAdd(&lhist[(unsigned)dst[e] / BKTW], 1);
    __syncthreads();
    bh[t * NBLK1 + blk] = lhist[t];
}

// k2: per-bucket exclusive scan over the 200 block counts (in place);
// btotal[b] = bucket total.
__global__ __launch_bounds__(256) void scan_buckets_kernel(
    int* __restrict__ bh, int* __restrict__ btotal)
{
    __shared__ int sb[256];
    const int t = threadIdx.x, b = blockIdx.x;
    const int v = (t < NBLK1) ? bh[b * NBLK1 + t] : 0;
    sb[t] = v;
    __syncthreads();
    int x = v;
    for (int off = 1; off < 256; off <<= 1) {
        const int add = (t >= off) ? sb[t - off] : 0;
        __syncthreads();
        x += add;
        sb[t] = x;
        __syncthreads();
    }
    if (t < NBLK1) bh[b * NBLK1 + t] = x - v;   // exclusive within bucket
    if (t == 255) btotal[b] = x;
}

// k3: exclusive scan of 256 bucket totals -> bstart[257]
__global__ __launch_bounds__(256) void scan_totals_kernel(
    const int* __restrict__ btotal, int* __restrict__ bstart)
{
    __shared__ int sb[256];
    const int t = threadIdx.x;
    const int v = btotal[t];
    sb[t] = v;
    __syncthreads();
    int x = v;
    for (int off = 1; off < 256; off <<= 1) {
        const int add = (t >= off) ? sb[t - off] : 0;
        __syncthreads();
        x += add;
        sb[t] = x;
        __syncthreads();
    }
    bstart[t] = x - v;
    if (t == 255) bstart[256] = x;
}

// k4: scatter edges into bucket-grouped gbuf; value packed (local_dst<<16)|src
// (src < 50000 < 2^16). Writes are contiguous runs per (blk,bucket).
__global__ __launch_bounds__(256) void scatter_bucket_kernel(
    const int* __restrict__ src, const int* __restrict__ dst,
    const int* __restrict__ bh, const int* __restrict__ bstart,
    int* __restrict__ gbuf)
{
    __shared__ int lbase[NBKT];
    __shared__ int lcur[NBKT];
    const int t = threadIdx.x, blk = blockIdx.x;
    lbase[t] = bstart[t] + bh[t * NBLK1 + blk];
    lcur[t] = 0;
    __syncthreads();
    const int e0 = blk * CHUNK1, e1 = e0 + CHUNK1;
    for (int e = e0 + t; e < e1; e += 256) {
        const int d = dst[e];
        const unsigned b = (unsigned)d / BKTW;
        const int ld = d - (int)b * BKTW;
        const int r = atomicAdd(&lcur[b], 1);
        gbuf[lbase[b] + r] = (ld << 16) | src[e];
    }
}

// k5: one block per bucket: LDS counting sort over <=196 local dsts;
// writes perm (src ids grouped by dst) and row_ptr.
__global__ __launch_bounds__(256) void sort_bucket_kernel(
    const int* __restrict__ gbuf, const int* __restrict__ bstart,
    int* __restrict__ perm, int* __restrict__ rowp)
{
    __shared__ int lhist[NBKT];
    __shared__ int lscan[NBKT];
    __shared__ int lcur[NBKT];
    const int t = threadIdx.x, b = blockIdx.x;
    const int base = bstart[b];
    const int cnt  = bstart[b + 1] - base;
    const int n0   = b * BKTW;

    lhist[t] = 0;
    lcur[t] = 0;
    __syncthreads();
    for (int i = t; i < cnt; i += 256)
        atomicAdd(&lhist[gbuf[base + i] >> 16], 1);
    __syncthreads();

    const int v = lhist[t];
    lscan[t] = v;
    __syncthreads();
    int x = v;
    for (int off = 1; off < 256; off <<= 1) {
        const int add = (t >= off) ? lscan[t - off] : 0;
        __syncthreads();
        x += add;
        lscan[t] = x;
        __syncthreads();
    }
    const int excl = x - v;
    __syncthreads();
    lscan[t] = excl;

    const int n = n0 + t;
    if (t < BKTW && n < N_NODES) rowp[n] = base + excl;
    if (b == NBKT - 1 && t == 0) rowp[N_NODES] = bstart[NBKT];
    __syncthreads();

    for (int i = t; i < cnt; i += 256) {
        const int e = gbuf[base + i];
        const int ld = e >> 16;
        const int r = atomicAdd(&lcur[ld], 1);
        perm[base + lscan[ld] + r] = e & 0xFFFF;
    }
}

// ---------------------------------------------------------------------------
// gather: block (128 thr) per dst node. Phase 1: w[e][h] once per (edge,head)
// via float2 score loads; phase 2: lean fp16-z accumulate. Zero atomics.
// ---------------------------------------------------------------------------
__global__ __launch_bounds__(128) void gather_kernel(
    const int* __restrict__ row_ptr, const int* __restrict__ perm,
    const _Float16* __restrict__ z,
    const float* __restrict__ s_src, const float* __restrict__ s_dst,
    float* __restrict__ out, const int apply_elu)
{
    __shared__ int   se_l[32];
    __shared__ float w_l[32][9];   // pad 9 to spread banks
    __shared__ float sdl[8];

    const int n = blockIdx.x;
    const int t = threadIdx.x;
    const int c = t;
    const int h = t >> 4;
    const int start = row_ptr[n];
    const int end   = row_ptr[n + 1];
    if (t < 8) sdl[t] = s_dst[n * 8 + t];
    __syncthreads();

    float acc = 0.f, wsum = 0.f;

    for (int j0 = start; j0 < end; j0 += 32) {
        const int cnt = min(32, end - j0);
        __syncthreads();
        {
            const int j = t & 31, hp = t >> 5;   // head-pair 0..3
            if (j < cnt) {
                const int se = perm[j0 + j];
                if (hp == 0) se_l[j] = se;
                const float2 sv = *(const float2*)&s_src[se * 8 + hp * 2];
                float s0 = sv.x + sdl[hp * 2];
                float s1 = sv.y + sdl[hp * 2 + 1];
                s0 = s0 > 0.f ? s0 : NEG_SLOPE * s0;
                s1 = s1 > 0.f ? s1 : NEG_SLOPE * s1;
                w_l[j][hp * 2]     = __expf(s0);
                w_l[j][hp * 2 + 1] = __expf(s1);
            }
        }
        __syncthreads();
#pragma unroll 4
        for (int j = 0; j < cnt; j++) {
            const float w = w_l[j][h];
            wsum += w;
            acc = fmaf(w, (float)z[se_l[j] * 128 + c], acc);
        }
    }

    float o = (end > start) ? acc / wsum : 0.f;
    if (apply_elu) o = o > 0.f ? o : expm1f(o);
    out[n * 128 + c] = o;
}

extern "C" void kernel_launch(void* const* d_in, const int* in_sizes, int n_in,
                              void* d_out, int out_size, void* d_ws, size_t ws_size,
                              hipStream_t stream) {
    const float* x    = (const float*)d_in[0];
    const int*   src  = (const int*)d_in[1];
    const int*   dst  = (const int*)d_in[2];
    const float* W1   = (const float*)d_in[3];
    const float* a1s  = (const float*)d_in[4];
    const float* a1d  = (const float*)d_in[5];
    const float* W2   = (const float*)d_in[6];
    const float* a2s  = (const float*)d_in[7];
    const float* a2d  = (const float*)d_in[8];
    float* out = (float*)d_out;

    // workspace carve (16B-aligned chunks)
    char* p = (char*)d_ws;
    _Float16* z  = (_Float16*)p;  p += (size_t)N_NODES * 128 * 2;       // 12.8MB
    float* ssrc  = (float*)p;     p += (size_t)N_NODES * 8 * 4;         // 1.6MB
    float* sdst  = (float*)p;     p += (size_t)N_NODES * 8 * 4;         // 1.6MB
    int*   rowp  = (int*)p;       p += ((size_t)N_NODES + 4) * 4;       // 200KB
    int*   bh    = (int*)p;       p += (size_t)NBKT * NBLK1 * 4;        // 205KB
    int*   btot  = (int*)p;       p += (size_t)NBKT * 4;
    int*   bstart= (int*)p;       p += ((size_t)NBKT + 4) * 4;
    int*   gbuf  = (int*)p;       p += (size_t)N_EDGES * 4;             // 6.4MB
    int*   perm  = (int*)p;       p += (size_t)N_EDGES * 4;             // 6.4MB

    const int PROJ_GRID  = 391;
    const int SCORE_GRID = (N_NODES * 8 + 255) / 256;

    // ---- CSR build v2 (shared by both layers) ----
    hist_bucket_kernel<<<NBLK1, 256, 0, stream>>>(dst, bh);
    scan_buckets_kernel<<<NBKT, 256, 0, stream>>>(bh, btot);
    scan_totals_kernel<<<1, 256, 0, stream>>>(btot, bstart);
    scatter_bucket_kernel<<<NBLK1, 256, 0, stream>>>(src, dst, bh, bstart, gbuf);
    sort_bucket_kernel<<<NBKT, 256, 0, stream>>>(gbuf, bstart, perm, rowp);

    // ---- layer 1 ----
    proj_mfma_kernel<<<PROJ_GRID, 256, 0, stream>>>(x, W1, z);
    score_kernel<<<SCORE_GRID, 256, 0, stream>>>(z, a1s, a1d, ssrc, sdst);
    gather_kernel<<<N_NODES, 128, 0, stream>>>(rowp, perm, z, ssrc, sdst, out, 1);

    // ---- layer 2 ----
    proj_mfma_kernel<<<PROJ_GRID, 256, 0, stream>>>(out, W2, z);
    score_kernel<<<SCORE_GRID, 256, 0, stream>>>(z, a2s, a2d, ssrc, sdst);
    gather_kernel<<<N_NODES, 128, 0, stream>>>(rowp, perm, z, ssrc, sdst, out, 0);
}

// Round 6
// 218.804 us; speedup vs baseline: 8.6349x; 1.1513x over previous
//
#include <hip/hip_runtime.h>
#include <hip/hip_bf16.h>

#define N_NODES 50000
#define N_EDGES 1600000
#define NEG_SLOPE 0.01f
#define WPAD 136   // k-stride (fp16) for LDS-staged W

#define NBKT 256   // dst buckets
#define BKTW 196   // bucket width: 196*256 = 50176 >= 50000
#define NBLK1 200  // pass-1 blocks
#define CHUNK1 8000 // 200*8000 = 1.6M edges exactly

typedef _Float16 v8h __attribute__((ext_vector_type(8)));
typedef _Float16 v2h __attribute__((ext_vector_type(2)));
typedef float v4f __attribute__((ext_vector_type(4)));

// ---------------------------------------------------------------------------
// proj: z[n, h*16+col] = sum_d x[n,d] * W[h,d,col], fp16 MFMA 16x16x32.
// A-frag loads via float4 (2 VMEM instrs instead of 8 scalar dwords).
// ---------------------------------------------------------------------------
__global__ __launch_bounds__(256) void proj_mfma_kernel(
    const float* __restrict__ x,
    const float* __restrict__ W,
    _Float16* __restrict__ z)
{
    __shared__ _Float16 Wl[128 * WPAD];

    const int t = threadIdx.x;
    for (int i = t; i < 16384; i += 256) {
        const int h = i >> 11, k = (i >> 4) & 127, col = i & 15;
        Wl[(h * 16 + col) * WPAD + k] = (_Float16)W[i];
    }
    __syncthreads();

    const int wid = t >> 6;
    const int l   = t & 63;
    const int lc  = l & 15;
    const int kg  = l >> 4;

    const int nwaves = gridDim.x * 4;
    for (int tile = blockIdx.x * 4 + wid; tile < N_NODES / 16; tile += nwaves) {
        const int n0 = tile * 16;
        v4f acc[8];
#pragma unroll
        for (int ht = 0; ht < 8; ht++) acc[ht] = (v4f)0.f;

#pragma unroll
        for (int kb = 0; kb < 4; kb++) {
            const float4* xp = (const float4*)&x[(n0 + lc) * 128 + kb * 32 + kg * 8];
            const float4 xa = xp[0];
            const float4 xb = xp[1];
            v8h a;
            a[0] = (_Float16)xa.x; a[1] = (_Float16)xa.y;
            a[2] = (_Float16)xa.z; a[3] = (_Float16)xa.w;
            a[4] = (_Float16)xb.x; a[5] = (_Float16)xb.y;
            a[6] = (_Float16)xb.z; a[7] = (_Float16)xb.w;
#pragma unroll
            for (int ht = 0; ht < 8; ht++) {
                const v8h b = *(const v8h*)&Wl[(ht * 16 + lc) * WPAD + kb * 32 + kg * 8];
                acc[ht] = __builtin_amdgcn_mfma_f32_16x16x32_f16(a, b, acc[ht], 0, 0, 0);
            }
        }

        _Float16* zp = &z[(n0 + 4 * kg) * 128 + lc];
#pragma unroll
        for (int ht = 0; ht < 8; ht++)
#pragma unroll
            for (int i = 0; i < 4; i++)
                zp[i * 128 + ht * 16] = (_Float16)acc[ht][i];
    }
}

// ---------------------------------------------------------------------------
// score: s_src[n,h], s_dst[n,h] from fp16 z.
// ---------------------------------------------------------------------------
__global__ __launch_bounds__(256) void score_kernel(
    const _Float16* __restrict__ z,
    const float* __restrict__ a_src, const float* __restrict__ a_dst,
    float* __restrict__ s_src, float* __restrict__ s_dst)
{
    __shared__ float asl[128], adl[128];
    const int t = threadIdx.x;
    if (t < 128) { asl[t] = a_src[t]; adl[t] = a_dst[t]; }
    __syncthreads();

    const int idx = blockIdx.x * 256 + t;
    if (idx >= N_NODES * 8) return;
    const int n = idx >> 3, h = idx & 7;

    const v8h z0 = *(const v8h*)&z[n * 128 + h * 16];
    const v8h z1 = *(const v8h*)&z[n * 128 + h * 16 + 8];
    float ss = 0.f, sd = 0.f;
#pragma unroll
    for (int j = 0; j < 8; j++) {
        ss = fmaf((float)z0[j], asl[h * 16 + j], ss);
        sd = fmaf((float)z0[j], adl[h * 16 + j], sd);
    }
#pragma unroll
    for (int j = 0; j < 8; j++) {
        ss = fmaf((float)z1[j], asl[h * 16 + 8 + j], ss);
        sd = fmaf((float)z1[j], adl[h * 16 + 8 + j], sd);
    }
    s_src[idx] = ss;
    s_dst[idx] = sd;
}

// ---------------------------------------------------------------------------
// CSR build v2 (unchanged from R5): two-level bucket sort, block-local writes.
// ---------------------------------------------------------------------------
__global__ __launch_bounds__(256) void hist_bucket_kernel(
    const int* __restrict__ dst, int* __restrict__ bh)
{
    __shared__ int lhist[NBKT];
    const int t = threadIdx.x, blk = blockIdx.x;
    lhist[t] = 0;
    __syncthreads();
    const int e0 = blk * CHUNK1, e1 = e0 + CHUNK1;
    for (int e = e0 + t; e < e1; e += 256)
        atomicAdd(&lhist[(unsigned)dst[e] / BKTW], 1);
    __syncthreads();
    bh[t * NBLK1 + blk] = lhist[t];
}

__global__ __launch_bounds__(256) void scan_buckets_kernel(
    int* __restrict__ bh, int* __restrict__ btotal)
{
    __shared__ int sb[256];
    const int t = threadIdx.x, b = blockIdx.x;
    const int v = (t < NBLK1) ? bh[b * NBLK1 + t] : 0;
    sb[t] = v;
    __syncthreads();
    int x = v;
    for (int off = 1; off < 256; off <<= 1) {
        const int add = (t >= off) ? sb[t - off] : 0;
        __syncthreads();
        x += add;
        sb[t] = x;
        __syncthreads();
    }
    if (t < NBLK1) bh[b * NBLK1 + t] = x - v;
    if (t == 255) btotal[b] = x;
}

__global__ __launch_bounds__(256) void scan_totals_kernel(
    const int* __restrict__ btotal, int* __restrict__ bstart)
{
    __shared__ int sb[256];
    const int t = threadIdx.x;
    const int v = btotal[t];
    sb[t] = v;
    __syncthreads();
    int x = v;
    for (int off = 1; off < 256; off <<= 1) {
        const int add = (t >= off) ? sb[t - off] : 0;
        __syncthreads();
        x += add;
        sb[t] = x;
        __syncthreads();
    }
    bstart[t] = x - v;
    if (t == 255) bstart[256] = x;
}

__global__ __launch_bounds__(256) void scatter_bucket_kernel(
    const int* __restrict__ src, const int* __restrict__ dst,
    const int* __restrict__ bh, const int* __restrict__ bstart,
    int* __restrict__ gbuf)
{
    __shared__ int lbase[NBKT];
    __shared__ int lcur[NBKT];
    const int t = threadIdx.x, blk = blockIdx.x;
    lbase[t] = bstart[t] + bh[t * NBLK1 + blk];
    lcur[t] = 0;
    __syncthreads();
    const int e0 = blk * CHUNK1, e1 = e0 + CHUNK1;
    for (int e = e0 + t; e < e1; e += 256) {
        const int d = dst[e];
        const unsigned b = (unsigned)d / BKTW;
        const int ld = d - (int)b * BKTW;
        const int r = atomicAdd(&lcur[b], 1);
        gbuf[lbase[b] + r] = (ld << 16) | src[e];
    }
}

__global__ __launch_bounds__(256) void sort_bucket_kernel(
    const int* __restrict__ gbuf, const int* __restrict__ bstart,
    int* __restrict__ perm, int* __restrict__ rowp)
{
    __shared__ int lhist[NBKT];
    __shared__ int lscan[NBKT];
    __shared__ int lcur[NBKT];
    const int t = threadIdx.x, b = blockIdx.x;
    const int base = bstart[b];
    const int cnt  = bstart[b + 1] - base;
    const int n0   = b * BKTW;

    lhist[t] = 0;
    lcur[t] = 0;
    __syncthreads();
    for (int i = t; i < cnt; i += 256)
        atomicAdd(&lhist[gbuf[base + i] >> 16], 1);
    __syncthreads();

    const int v = lhist[t];
    lscan[t] = v;
    __syncthreads();
    int x = v;
    for (int off = 1; off < 256; off <<= 1) {
        const int add = (t >= off) ? lscan[t - off] : 0;
        __syncthreads();
        x += add;
        lscan[t] = x;
        __syncthreads();
    }
    const int excl = x - v;
    __syncthreads();
    lscan[t] = excl;

    const int n = n0 + t;
    if (t < BKTW && n < N_NODES) rowp[n] = base + excl;
    if (b == NBKT - 1 && t == 0) rowp[N_NODES] = bstart[NBKT];
    __syncthreads();

    for (int i = t; i < cnt; i += 256) {
        const int e = gbuf[base + i];
        const int ld = e >> 16;
        const int r = atomicAdd(&lcur[ld], 1);
        perm[base + lscan[ld] + r] = e & 0xFFFF;
    }
}

// ---------------------------------------------------------------------------
// gather v3: ONE WAVE per dst node (block=128 = 2 waves = 2 nodes, zero
// barriers). Lane owns channel pair (2l, 2l+1) (same head h=l>>3): per edge
// 1 dword load + 2 cvt + 2 fma. Weights computed 8 edges/round, lane =
// (edge-slot je, head h8); round r+1's random perm/s_src loads are issued
// before round r's FMA loop (software pipeline). Invalid slots w=0 ->
// branch-free inner loop. Wave-private LDS, no conflicts (broadcast reads).
// ---------------------------------------------------------------------------
__global__ __launch_bounds__(128) void gather_kernel(
    const int* __restrict__ row_ptr, const int* __restrict__ perm,
    const _Float16* __restrict__ z,
    const float* __restrict__ s_src, const float* __restrict__ s_dst,
    float* __restrict__ out, const int apply_elu)
{
    __shared__ int   se_l[2][8];
    __shared__ float w_l[2][8][8];

    const int t  = threadIdx.x;
    const int wv = t >> 6;          // wave id = node sub-index
    const int l  = t & 63;
    const int n  = blockIdx.x * 2 + wv;   // N_NODES even -> always < N

    const int h8 = l & 7;           // head slot (phase 1)
    const int je = l >> 3;          // edge slot (phase 1)
    const int c0 = 2 * l;           // channel pair (phase 2)
    const int h  = l >> 3;          // head of channels (c0,c0+1)

    const int start = row_ptr[n];
    const int end   = row_ptr[n + 1];
    const float sd  = s_dst[n * 8 + h8];

    float acc0 = 0.f, acc1 = 0.f, wsum = 0.f;

    // prologue: round 0 weights into registers
    int   se_r = 0;
    float w_r  = 0.f;
    {
        const int j = start + je;
        if (j < end) {
            se_r = perm[j];
            float s = s_src[se_r * 8 + h8] + sd;
            s = s > 0.f ? s : NEG_SLOPE * s;
            w_r = __expf(s);
        }
    }

    for (int j0 = start; j0 < end; j0 += 8) {
        // publish current round to wave-private LDS (no barrier needed)
        if (h8 == 0) se_l[wv][je] = se_r;
        w_l[wv][je][h8] = w_r;

        // prefetch next round (latency hidden under the FMA loop below)
        int   se_n = 0;
        float w_n  = 0.f;
        {
            const int j = j0 + 8 + je;
            if (j < end) {
                se_n = perm[j];
                float s = s_src[se_n * 8 + h8] + sd;
                s = s > 0.f ? s : NEG_SLOPE * s;
                w_n = __expf(s);
            }
        }

#pragma unroll
        for (int j = 0; j < 8; j++) {
            const float w  = w_l[wv][j][h];
            const int   se = se_l[wv][j];
            const v2h   zv = *(const v2h*)&z[se * 128 + c0];
            wsum += w;
            acc0 = fmaf(w, (float)zv[0], acc0);
            acc1 = fmaf(w, (float)zv[1], acc1);
        }

        se_r = se_n;
        w_r  = w_n;
    }

    const float inv = (wsum > 0.f) ? 1.f / wsum : 0.f;
    float o0 = acc0 * inv;
    float o1 = acc1 * inv;
    if (apply_elu) {
        o0 = o0 > 0.f ? o0 : expm1f(o0);
        o1 = o1 > 0.f ? o1 : expm1f(o1);
    }
    *(float2*)&out[n * 128 + c0] = make_float2(o0, o1);
}

extern "C" void kernel_launch(void* const* d_in, const int* in_sizes, int n_in,
                              void* d_out, int out_size, void* d_ws, size_t ws_size,
                              hipStream_t stream) {
    const float* x    = (const float*)d_in[0];
    const int*   src  = (const int*)d_in[1];
    const int*   dst  = (const int*)d_in[2];
    const float* W1   = (const float*)d_in[3];
    const float* a1s  = (const float*)d_in[4];
    const float* a1d  = (const float*)d_in[5];
    const float* W2   = (const float*)d_in[6];
    const float* a2s  = (const float*)d_in[7];
    const float* a2d  = (const float*)d_in[8];
    float* out = (float*)d_out;

    // workspace carve
    char* p = (char*)d_ws;
    _Float16* z  = (_Float16*)p;  p += (size_t)N_NODES * 128 * 2;       // 12.8MB
    float* ssrc  = (float*)p;     p += (size_t)N_NODES * 8 * 4;         // 1.6MB
    float* sdst  = (float*)p;     p += (size_t)N_NODES * 8 * 4;         // 1.6MB
    int*   rowp  = (int*)p;       p += ((size_t)N_NODES + 4) * 4;       // 200KB
    int*   bh    = (int*)p;       p += (size_t)NBKT * NBLK1 * 4;        // 205KB
    int*   btot  = (int*)p;       p += (size_t)NBKT * 4;
    int*   bstart= (int*)p;       p += ((size_t)NBKT + 4) * 4;
    int*   gbuf  = (int*)p;       p += (size_t)N_EDGES * 4;             // 6.4MB
    int*   perm  = (int*)p;       p += (size_t)N_EDGES * 4;             // 6.4MB

    const int PROJ_GRID  = 391;
    const int SCORE_GRID = (N_NODES * 8 + 255) / 256;

    // ---- CSR build (shared by both layers) ----
    hist_bucket_kernel<<<NBLK1, 256, 0, stream>>>(dst, bh);
    scan_buckets_kernel<<<NBKT, 256, 0, stream>>>(bh, btot);
    scan_totals_kernel<<<1, 256, 0, stream>>>(btot, bstart);
    scatter_bucket_kernel<<<NBLK1, 256, 0, stream>>>(src, dst, bh, bstart, gbuf);
    sort_bucket_kernel<<<NBKT, 256, 0, stream>>>(gbuf, bstart, perm, rowp);

    // ---- layer 1 ----
    proj_mfma_kernel<<<PROJ_GRID, 256, 0, stream>>>(x, W1, z);
    score_kernel<<<SCORE_GRID, 256, 0, stream>>>(z, a1s, a1d, ssrc, sdst);
    gather_kernel<<<N_NODES / 2, 128, 0, stream>>>(rowp, perm, z, ssrc, sdst, out, 1);

    // ---- layer 2 ----
    proj_mfma_kernel<<<PROJ_GRID, 256, 0, stream>>>(out, W2, z);
    score_kernel<<<SCORE_GRID, 256, 0, stream>>>(z, a2s, a2d, ssrc, sdst);
    gather_kernel<<<N_NODES / 2, 128, 0, stream>>>(rowp, perm, z, ssrc, sdst, out, 0);
}